// Round 9
// baseline (341.946 us; speedup 1.0000x reference)
//
#include <hip/hip_runtime.h>
#include <hip/hip_bf16.h>

typedef __attribute__((ext_vector_type(4))) float f32x4;
typedef __attribute__((ext_vector_type(8))) short short8;
typedef __attribute__((ext_vector_type(4))) short short4v;
typedef __attribute__((ext_vector_type(2))) unsigned int u32x2;
typedef unsigned short ushort_t;

__device__ __forceinline__ f32x4 mfma16(short8 a, short8 b, f32x4 c) {
  return __builtin_amdgcn_mfma_f32_16x16x32_bf16(a, b, c, 0, 0, 0);
}

__device__ __forceinline__ void gload_lds16(const void* g, void* l) {
  __builtin_amdgcn_global_load_lds(
      (const __attribute__((address_space(1))) void*)g,
      (__attribute__((address_space(3))) void*)l, 16, 0, 0);
}

__device__ __forceinline__ ushort_t f2bf(float f) {
  union { float f; unsigned int u; } un; un.f = f;
  unsigned int u = un.u;
  u += 0x7fffu + ((u >> 16) & 1u);  // round-to-nearest-even
  return (ushort_t)(u >> 16);
}

__device__ __forceinline__ float bf2f(ushort_t u) {
  union { unsigned int i; float f; } c; c.i = ((unsigned int)u) << 16;
  return c.f;
}

__device__ __forceinline__ float fast_exp2(float x) {
#if __has_builtin(__builtin_amdgcn_exp2f)
  return __builtin_amdgcn_exp2f(x);
#else
  return exp2f(x);
#endif
}

__device__ __forceinline__ unsigned int cvt_pk_bf16(float a, float b) {
  unsigned int r;
  asm("v_cvt_pk_bf16_f32 %0, %1, %2" : "=v"(r) : "v"(a), "v"(b));
  return r;
}

// ---------------------------------------------------------------------------
// fp32 (R x C) -> bf16 transposed (C x R)
// ---------------------------------------------------------------------------
__global__ __launch_bounds__(256) void tcvt_ker(const float* __restrict__ in,
                                                ushort_t* __restrict__ out,
                                                int R, int C) {
  __shared__ float t[64][65];
  const int tid = threadIdx.x;
  const int tr = blockIdx.y * 64;
  const int tc = blockIdx.x * 64;
#pragma unroll
  for (int it = 0; it < 4; ++it) {
    int r = it * 16 + (tid >> 4);
    int c4 = (tid & 15) * 4;
    f32x4 v = *(const f32x4*)&in[(size_t)(tr + r) * C + tc + c4];
#pragma unroll
    for (int e = 0; e < 4; ++e) t[r][c4 + e] = v[e];
  }
  __syncthreads();
#pragma unroll
  for (int it = 0; it < 4; ++it) {
    int idx = it * 256 + tid;
    int n = idx >> 4;
    int k4 = (idx & 15) * 4;
    short4v o;
#pragma unroll
    for (int e = 0; e < 4; ++e) o[e] = (short)f2bf(t[k4 + e][n]);
    *(short4v*)&out[(size_t)(tc + n) * R + tr + k4] = o;
  }
}

__global__ __launch_bounds__(256) void concat3_ker(const float* __restrict__ a,
                                                   const float* __restrict__ b,
                                                   const float* __restrict__ c,
                                                   float* __restrict__ o) {
  int i = blockIdx.x * 256 + threadIdx.x;
  if (i < 3072) o[i] = i < 1024 ? a[i] : (i < 2048 ? b[i - 1024] : c[i - 2048]);
}

// mask -> additive float bias (0 or -1e9)
__global__ __launch_bounds__(256) void mbias_ker(const int* __restrict__ emask,
                                                 float* __restrict__ mb) {
  int i = blockIdx.x * 256 + threadIdx.x;
  if (i < 8192) mb[i] = emask[i] ? 0.f : -1e9f;
}

// ---------------------------------------------------------------------------
// LayerNorm, f32 input variant. One wave per row of 1024.
// ---------------------------------------------------------------------------
__global__ __launch_bounds__(256) void ln_ker(const float* __restrict__ x,
                                              const float* __restrict__ g,
                                              const float* __restrict__ b,
                                              ushort_t* __restrict__ out) {
  const int wave = threadIdx.x >> 6, lane = threadIdx.x & 63;
  const size_t row = (size_t)blockIdx.x * 4 + wave;
  const float* xr = x + row * 1024;
  f32x4 v[4];
  float s = 0.f, sq = 0.f;
#pragma unroll
  for (int jj = 0; jj < 4; ++jj) {
    v[jj] = *(const f32x4*)&xr[lane * 4 + jj * 256];
#pragma unroll
    for (int e = 0; e < 4; ++e) { s += v[jj][e]; sq += v[jj][e] * v[jj][e]; }
  }
#pragma unroll
  for (int off = 1; off < 64; off <<= 1) {
    s += __shfl_xor(s, off);
    sq += __shfl_xor(sq, off);
  }
  const float mu = s * (1.0f / 1024.0f);
  const float var = sq * (1.0f / 1024.0f) - mu * mu;
  const float rst = rsqrtf(var + 1e-6f);
#pragma unroll
  for (int jj = 0; jj < 4; ++jj) {
    int col = lane * 4 + jj * 256;
    f32x4 gv = *(const f32x4*)&g[col];
    f32x4 bv = *(const f32x4*)&b[col];
    short4v o;
#pragma unroll
    for (int e = 0; e < 4; ++e)
      o[e] = (short)f2bf((v[jj][e] - mu) * rst * gv[e] + bv[e]);
    *(short4v*)&out[row * 1024 + col] = o;
  }
}

// ---------------------------------------------------------------------------
// LayerNorm, bf16 input variant. One wave per row of 1024.
// ---------------------------------------------------------------------------
__global__ __launch_bounds__(256) void ln_bf16_ker(const ushort_t* __restrict__ x,
                                                   const float* __restrict__ g,
                                                   const float* __restrict__ b,
                                                   ushort_t* __restrict__ out) {
  const int wave = threadIdx.x >> 6, lane = threadIdx.x & 63;
  const size_t row = (size_t)blockIdx.x * 4 + wave;
  const ushort_t* xr = x + row * 1024;
  float vf[16];
  float s = 0.f, sq = 0.f;
#pragma unroll
  for (int jj = 0; jj < 2; ++jj) {
    short8 v8 = *(const short8*)&xr[lane * 8 + jj * 512];
#pragma unroll
    for (int e = 0; e < 8; ++e) {
      float f = bf2f((ushort_t)v8[e]);
      vf[jj * 8 + e] = f;
      s += f; sq += f * f;
    }
  }
#pragma unroll
  for (int off = 1; off < 64; off <<= 1) {
    s += __shfl_xor(s, off);
    sq += __shfl_xor(sq, off);
  }
  const float mu = s * (1.0f / 1024.0f);
  const float var = sq * (1.0f / 1024.0f) - mu * mu;
  const float rst = rsqrtf(var + 1e-6f);
#pragma unroll
  for (int jj = 0; jj < 2; ++jj) {
    int col = lane * 8 + jj * 512;
    short8 o;
#pragma unroll
    for (int q = 0; q < 2; ++q) {
      f32x4 gv = *(const f32x4*)&g[col + q * 4];
      f32x4 bv = *(const f32x4*)&b[col + q * 4];
#pragma unroll
      for (int e = 0; e < 4; ++e)
        o[q * 4 + e] =
            (short)f2bf((vf[jj * 8 + q * 4 + e] - mu) * rst * gv[e] + bv[e]);
    }
    *(short8*)&out[row * 1024 + col] = o;
  }
}

// ---------------------------------------------------------------------------
// V pre-transpose: qkv V block -> Vt[bh][d][kv + kappa], kappa = (k&15)*4+(k>>4)
// ---------------------------------------------------------------------------
__global__ __launch_bounds__(256) void vtrans_ker(const ushort_t* __restrict__ qkv,
                                                  ushort_t* __restrict__ vt) {
  __shared__ ushort_t l[64][72];
  const int tid = threadIdx.x;
  const int tile = blockIdx.x;
  const int bh = blockIdx.y;
  const int b = bh >> 4, h = bh & 15;
  const size_t base = (size_t)b * 1024 * 3072 + 2048 + h * 64;
#pragma unroll
  for (int it = 0; it < 2; ++it) {
    int idx = it * 256 + tid;
    int row = idx >> 3, c8 = (idx & 7) * 8;
    short8 v = *(const short8*)(qkv + base + (size_t)(tile * 64 + row) * 3072 + c8);
    *(short8*)&l[row][c8] = v;
  }
  __syncthreads();
#pragma unroll
  for (int it = 0; it < 2; ++it) {
    int idx = it * 256 + tid;
    int d = idx >> 3, k0 = (idx & 7) * 8;
    short8 o;
#pragma unroll
    for (int m = 0; m < 8; ++m) {
      int kp = k0 + m;
      int key = (kp & 3) * 16 + (kp >> 2);
      o[m] = (short)l[key][d];
    }
    *(short8*)&vt[((size_t)bh * 64 + d) * 1024 + tile * 64 + k0] = o;
  }
}

// ---------------------------------------------------------------------------
// 4-phase GEMM (m201-style)  C(MxN) = A(MxK,bf16) * Bt(NxK,bf16)^T + bias
// Per K-tile t (buf = t&1), uniform phases of 16 MFMA:
//  ph0: read fa(A0),fb0 ; stage A1(t+1)->buf^1 ; BAR ; lgkm0 ; MFMA(A0,B0) ; BAR
//  ph1: read fb1        ; stage A0(t+2)->buf   ; BAR ; lgkm0 ; MFMA(A0,B1) ; BAR
//  ph2: read fa(A1)     ; stage B0(t+2)->buf   ; BAR ; lgkm0 ; MFMA(A1,B1) ; BAR
//  ph3:                   stage B1(t+2)->buf   ; BAR ;         MFMA(A1,B0) ; vmcnt(VN) ; BAR
// lgkm0 = asm s_waitcnt lgkmcnt(0) + sched_barrier(0) (rule 18) -> dense MFMA bursts.
// vmcnt(VN=LA+2LB) retires exactly tile t+1; {A0,B0,B1}(t+2) stay in flight.
// MODE 0: bf16 | 1: bf16+relu | 3: bf16 + f32 resid | 4: f32 + bf16 resid
// ---------------------------------------------------------------------------
template <int MODE, int BM, int BN>
__global__ __launch_bounds__(512, 1) void gemm8_ker(
    const ushort_t* __restrict__ A, const ushort_t* __restrict__ Bt,
    const float* __restrict__ bias, const void* __restrict__ resid,
    void* __restrict__ Cout, int M, int N, int K) {
  constexpr int MR = BM / 32;
  constexpr int NR = BN / 64;
  constexpr int LA = BM / 128;
  constexpr int LB = BN / 128;
  constexpr int HALF_A = (BM / 2) * 128;
  constexpr int HALF_B = (BN / 2) * 128;
  constexpr int TILE = 2 * HALF_A + 2 * HALF_B;
  constexpr int VN = LA + 2 * LB;

  __shared__ alignas(128) char lds[2 * TILE];

  const int tid = threadIdx.x;
  const int wave = tid >> 6, lane = tid & 63;
  const int g = lane >> 4, l15 = lane & 15;
  const int wr = wave >> 2, wc = wave & 3;

  const int nwg = gridDim.x * gridDim.y;
  int wg = blockIdx.y * gridDim.x + blockIdx.x;
  if ((nwg & 7) == 0) wg = (wg & 7) * (nwg >> 3) + (wg >> 3);
  const int bx = wg % gridDim.x, by = wg / gridDim.x;
  const int mbase = by * BM;
  const int nbase = bx * BN;
  const int NT = K >> 6;

  auto stage_A = [&](int bf, int h, int kt) {
    const ushort_t* sb = A + (size_t)(mbase + h * (BM / 2)) * K + kt * 64;
    char* dst = lds + bf * TILE + h * HALF_A;
#pragma unroll
    for (int it = 0; it < LA; ++it) {
      int li = it * 512 + tid;
      int r = li >> 3;
      int cs = ((tid & 7) * 16) ^ ((r & 7) << 4);
      gload_lds16((const char*)(sb + (size_t)r * K) + cs, dst + li * 16);
    }
  };
  auto stage_B = [&](int bf, int h, int kt) {
    const ushort_t* sb = Bt + (size_t)(nbase + h * (BN / 2)) * K + kt * 64;
    char* dst = lds + bf * TILE + 2 * HALF_A + h * HALF_B;
#pragma unroll
    for (int it = 0; it < LB; ++it) {
      int li = it * 512 + tid;
      int r = li >> 3;
      int cs = ((tid & 7) * 16) ^ ((r & 7) << 4);
      gload_lds16((const char*)(sb + (size_t)r * K) + cs, dst + li * 16);
    }
  };
  auto frag = [&](const char* slot, int r, int kk) -> short8 {
    const int cb = kk * 64 + g * 16;
    return *(const short8*)(slot + r * 128 + (cb ^ ((r & 7) << 4)));
  };

#define LGKM0_FENCE()                                   \
  asm volatile("s_waitcnt lgkmcnt(0)" ::: "memory");    \
  __builtin_amdgcn_sched_barrier(0)

  f32x4 acc[MR][NR];
  const f32x4 zf = {0.f, 0.f, 0.f, 0.f};
#pragma unroll
  for (int i = 0; i < MR; ++i)
#pragma unroll
    for (int j = 0; j < NR; ++j) acc[i][j] = zf;

  stage_A(0, 0, 0); stage_A(0, 1, 0); stage_B(0, 0, 0); stage_B(0, 1, 0);
  stage_A(1, 0, 1); stage_B(1, 0, 1); stage_B(1, 1, 1);
  asm volatile("s_waitcnt vmcnt(%0)" :: "n"(VN) : "memory");
  __builtin_amdgcn_s_barrier();

  short8 fa[MR / 2][2], fb0[NR / 2][2], fb1[NR / 2][2];

  for (int t = 0; t < NT; ++t) {
    const int buf = t & 1;
    const int k1 = (t + 1 < NT) ? t + 1 : NT - 1;
    const int k2 = (t + 2 < NT) ? t + 2 : NT - 1;
    const char* sA0 = lds + buf * TILE;
    const char* sA1 = sA0 + HALF_A;
    const char* sB0 = sA0 + 2 * HALF_A;
    const char* sB1 = sB0 + HALF_B;

    // ---- ph0 ----
#pragma unroll
    for (int ii = 0; ii < MR / 2; ++ii)
#pragma unroll
      for (int kk = 0; kk < 2; ++kk)
        fa[ii][kk] = frag(sA0, wr * (BM / 4) + ii * 16 + l15, kk);
#pragma unroll
    for (int jj = 0; jj < NR / 2; ++jj)
#pragma unroll
      for (int kk = 0; kk < 2; ++kk)
        fb0[jj][kk] = frag(sB0, wc * (BN / 8) + jj * 16 + l15, kk);
    stage_A(buf ^ 1, 1, k1);
    __builtin_amdgcn_s_barrier();
    LGKM0_FENCE();
    __builtin_amdgcn_s_setprio(1);
#pragma unroll
    for (int ii = 0; ii < MR / 2; ++ii)
#pragma unroll
      for (int jj = 0; jj < NR / 2; ++jj)
#pragma unroll
        for (int kk = 0; kk < 2; ++kk)
          acc[ii][jj] = mfma16(fa[ii][kk], fb0[jj][kk], acc[ii][jj]);
    __builtin_amdgcn_s_setprio(0);
    __builtin_amdgcn_s_barrier();

    // ---- ph1 ----
#pragma unroll
    for (int jj = 0; jj < NR / 2; ++jj)
#pragma unroll
      for (int kk = 0; kk < 2; ++kk)
        fb1[jj][kk] = frag(sB1, wc * (BN / 8) + jj * 16 + l15, kk);
    stage_A(buf, 0, k2);
    __builtin_amdgcn_s_barrier();
    LGKM0_FENCE();
    __builtin_amdgcn_s_setprio(1);
#pragma unroll
    for (int ii = 0; ii < MR / 2; ++ii)
#pragma unroll
      for (int jj = 0; jj < NR / 2; ++jj)
#pragma unroll
        for (int kk = 0; kk < 2; ++kk)
          acc[ii][jj + NR / 2] = mfma16(fa[ii][kk], fb1[jj][kk], acc[ii][jj + NR / 2]);
    __builtin_amdgcn_s_setprio(0);
    __builtin_amdgcn_s_barrier();

    // ---- ph2 ----
#pragma unroll
    for (int ii = 0; ii < MR / 2; ++ii)
#pragma unroll
      for (int kk = 0; kk < 2; ++kk)
        fa[ii][kk] = frag(sA1, wr * (BM / 4) + ii * 16 + l15, kk);
    stage_B(buf, 0, k2);
    __builtin_amdgcn_s_barrier();
    LGKM0_FENCE();
    __builtin_amdgcn_s_setprio(1);
#pragma unroll
    for (int ii = 0; ii < MR / 2; ++ii)
#pragma unroll
      for (int jj = 0; jj < NR / 2; ++jj)
#pragma unroll
        for (int kk = 0; kk < 2; ++kk)
          acc[ii + MR / 2][jj + NR / 2] =
              mfma16(fa[ii][kk], fb1[jj][kk], acc[ii + MR / 2][jj + NR / 2]);
    __builtin_amdgcn_s_setprio(0);
    __builtin_amdgcn_s_barrier();

    // ---- ph3 ----
    stage_B(buf, 1, k2);
    __builtin_amdgcn_s_barrier();
    __builtin_amdgcn_sched_barrier(0);
    __builtin_amdgcn_s_setprio(1);
#pragma unroll
    for (int ii = 0; ii < MR / 2; ++ii)
#pragma unroll
      for (int jj = 0; jj < NR / 2; ++jj)
#pragma unroll
        for (int kk = 0; kk < 2; ++kk)
          acc[ii + MR / 2][jj] = mfma16(fa[ii][kk], fb0[jj][kk], acc[ii + MR / 2][jj]);
    __builtin_amdgcn_s_setprio(0);
    asm volatile("s_waitcnt vmcnt(%0)" :: "n"(VN) : "memory");
    __builtin_amdgcn_s_barrier();
  }
#undef LGKM0_FENCE

  asm volatile("s_waitcnt vmcnt(0)" ::: "memory");

  float bcol[NR];
#pragma unroll
  for (int j = 0; j < NR; ++j) {
    const int bandj = j / (NR / 2), jj = j % (NR / 2);
    bcol[j] = bias[nbase + bandj * (BN / 2) + wc * (BN / 8) + jj * 16 + l15];
  }
#pragma unroll
  for (int i = 0; i < MR; ++i) {
    const int band = i / (MR / 2), ii = i % (MR / 2);
    const int rowb = mbase + band * (BM / 2) + wr * (BM / 4) + ii * 16 + g * 4;
#pragma unroll
    for (int r = 0; r < 4; ++r) {
      const int row = rowb + r;
#pragma unroll
      for (int j = 0; j < NR; ++j) {
        const int bandj = j / (NR / 2), jj = j % (NR / 2);
        const int col = nbase + bandj * (BN / 2) + wc * (BN / 8) + jj * 16 + l15;
        float v = acc[i][j][r] + bcol[j];
        if (MODE == 4) {
          float rv = bf2f(((const ushort_t*)resid)[(size_t)row * N + col]);
          ((float*)Cout)[(size_t)row * N + col] = rv + v;
        } else if (MODE == 3) {
          float rv = ((const float*)resid)[(size_t)row * N + col];
          ((ushort_t*)Cout)[(size_t)row * N + col] = f2bf(rv + v);
        } else {
          if (MODE == 1) v = fmaxf(v, 0.f);
          ((ushort_t*)Cout)[(size_t)row * N + col] = f2bf(v);
        }
      }
    }
  }
}

// ---------------------------------------------------------------------------
// Flash attention v5 (unchanged)
// ---------------------------------------------------------------------------
__global__ __launch_bounds__(256, 4) void attn_ker(const ushort_t* __restrict__ qkv,
                                                   const ushort_t* __restrict__ vt,
                                                   const float* __restrict__ mbias,
                                                   ushort_t* __restrict__ out) {
  __shared__ ushort_t lK[2][4096];
  __shared__ ushort_t lV[2][4096];
  __shared__ ushort_t lP[4][1024];
  const int tid = threadIdx.x;
  const int wave = tid >> 6, lane = tid & 63;
  const int g = lane >> 4, l15 = lane & 15;
  const int orig = blockIdx.y * 8 + blockIdx.x;
  const int swz = (orig & 7) * 128 + (orig >> 3);
  const int qp = swz & 7;
  const int bh = swz >> 3;
  const int b = bh >> 4, h = bh & 15;
  const int QS = 3072;
  const size_t base = (size_t)b * 1024 * QS;
  const int qoff = h * 64, koff = 1024 + h * 64;

  short8 qf[2][2];
#pragma unroll
  for (int s = 0; s < 2; ++s) {
    const int qrow = qp * 128 + s * 64 + wave * 16 + l15;
    const ushort_t* qpt = qkv + base + (size_t)qrow * QS + qoff + g * 8;
    qf[s][0] = *(const short8*)(qpt);
    qf[s][1] = *(const short8*)(qpt + 32);
  }
  f32x4 lsum4[2];
  f32x4 acco[2][4];
  const f32x4 zf = {0.f, 0.f, 0.f, 0.f};
#pragma unroll
  for (int s = 0; s < 2; ++s) {
    lsum4[s] = zf;
#pragma unroll
    for (int dj = 0; dj < 4; ++dj) acco[s][dj] = zf;
  }

  const float SCL = 0.125f * 1.44269504089f;
  const float* mbp = mbias + b * 1024 + l15;

  const int itrow = tid >> 3;
  const int c16 = ((tid & 7) * 16) ^ ((itrow & 7) << 4);
  const char* srcK = (const char*)(qkv + base + (size_t)itrow * QS + koff) + c16;
  const char* srcV = (const char*)(vt + ((size_t)bh * 64 + itrow) * 1024) + c16;
  constexpr int K_IT = 32 * 3072 * 2;
  constexpr int K_T  = 64 * 3072 * 2;
  constexpr int V_IT = 32 * 1024 * 2;
  constexpr int V_T  = 64 * 2;

  auto stage = [&](int bufi) {
    gload_lds16(srcK, &lK[bufi][tid * 8]);
    gload_lds16(srcK + K_IT, &lK[bufi][2048 + tid * 8]);
    gload_lds16(srcV, &lV[bufi][tid * 8]);
    gload_lds16(srcV + V_IT, &lV[bufi][2048 + tid * 8]);
  };

  stage(0);
  srcK += K_T; srcV += V_T;
  __syncthreads();

  for (int t = 0; t < 16; ++t) {
    const int buf = t & 1;
    if (t < 15) {
      stage(buf ^ 1);
      srcK += K_T; srcV += V_T;
    }
    const int kv = t * 64;
    float mbv[4];
#pragma unroll
    for (int j = 0; j < 4; ++j) mbv[j] = mbp[kv + j * 16];

    ushort_t* lPw = lP[wave];
#pragma unroll
    for (int s = 0; s < 2; ++s) {
      f32x4 sv[4];
#pragma unroll
      for (int j = 0; j < 4; ++j) {
        const int row = j * 16 + l15;
        const int sw = (l15 & 7) << 3;
        const short8 b0 = *(const short8*)&lK[buf][row * 64 + ((g * 8) ^ sw)];
        const short8 b1 = *(const short8*)&lK[buf][row * 64 + ((32 + g * 8) ^ sw)];
        f32x4 t2 = mfma16(qf[s][0], b0, zf);
        t2 = mfma16(qf[s][1], b1, t2);
#pragma unroll
        for (int e = 0; e < 4; ++e) t2[e] = t2[e] * SCL + mbv[j];
        sv[j] = t2;
      }

#pragma unroll
      for (int j = 0; j < 4; ++j) {
#pragma unroll
        for (int e = 0; e < 4; ++e) sv[j][e] = fast_exp2(sv[j][e]);
        lsum4[s] += sv[j];
      }

#pragma unroll
      for (int r = 0; r < 4; ++r) {
        const int q = g * 4 + r;
        u32x2 pk;
        pk[0] = cvt_pk_bf16(sv[0][r], sv[1][r]);
        pk[1] = cvt_pk_bf16(sv[2][r], sv[3][r]);
        *(u32x2*)&lPw[q * 64 + ((l15 * 4) ^ ((q & 7) << 3))] = pk;
      }

#pragma unroll
      for (int kk = 0; kk < 2; ++kk) {
        const short8 pa =
            *(const short8*)&lPw[l15 * 64 + ((kk * 32 + g * 8) ^ ((l15 & 7) << 3))];
#pragma unroll
        for (int dj = 0; dj < 4; ++dj) {
          const int drow = dj * 16 + l15;
          const short8 vb =
              *(const short8*)&lV[buf][drow * 64 + ((kk * 32 + g * 8) ^ ((drow & 7) << 3))];
          acco[s][dj] = mfma16(pa, vb, acco[s][dj]);
        }
      }
    }
    __syncthreads();
  }

#pragma unroll
  for (int s = 0; s < 2; ++s) {
#pragma unroll
    for (int r = 0; r < 4; ++r) {
      float tot = lsum4[s][r];
      tot += __shfl_xor(tot, 1);
      tot += __shfl_xor(tot, 2);
      tot += __shfl_xor(tot, 4);
      tot += __shfl_xor(tot, 8);
      const float inv = 1.0f / tot;
      const int row = qp * 128 + s * 64 + wave * 16 + g * 4 + r;
#pragma unroll
      for (int dj = 0; dj < 4; ++dj)
        out[((size_t)(b * 1024 + row)) * 1024 + h * 64 + dj * 16 + l15] =
            f2bf(acco[s][dj][r] * inv);
    }
  }
}

// ---------------------------------------------------------------------------
extern "C" void kernel_launch(void* const* d_in, const int* in_sizes, int n_in,
                              void* d_out, int out_size, void* d_ws, size_t ws_size,
                              hipStream_t stream) {
  const float* x    = (const float*)d_in[0];
  const int* emask  = (const int*)d_in[1];
  const float* ln1g = (const float*)d_in[2];
  const float* ln1b = (const float*)d_in[3];
  const float* Wq   = (const float*)d_in[4];
  const float* bq   = (const float*)d_in[5];
  const float* Wk   = (const float*)d_in[6];
  const float* bk   = (const float*)d_in[7];
  const float* Wv   = (const float*)d_in[8];
  const float* bv   = (const float*)d_in[9];
  const float* Wo   = (const float*)d_in[10];
  const float* bo   = (const float*)d_in[11];
  const float* ln2g = (const float*)d_in[12];
  const float* ln2b = (const float*)d_in[13];
  const float* W1   = (const float*)d_in[14];
  const float* b1   = (const float*)d_in[15];
  const float* W2   = (const float*)d_in[16];
  const float* b2   = (const float*)d_in[17];

  char* p = (char*)d_ws;
  auto carve = [&](size_t bytes) {
    char* r = p;
    p += (bytes + 255) & ~(size_t)255;
    return r;
  };
  ushort_t* WqkvT = (ushort_t*)carve((size_t)3072 * 1024 * 2);
  ushort_t* WoT   = (ushort_t*)carve((size_t)1024 * 1024 * 2);
  ushort_t* W1T   = (ushort_t*)carve((size_t)4096 * 1024 * 2);
  ushort_t* W2T   = (ushort_t*)carve((size_t)1024 * 4096 * 2);
  float*    bqkv  = (float*)carve(3072 * 4);
  float*    mb    = (float*)carve(8192 * 4);
  ushort_t* x1    = (ushort_t*)carve((size_t)8192 * 1024 * 2);
  ushort_t* qkvb  = (ushort_t*)carve((size_t)8192 * 3072 * 2);
  ushort_t* attnb = (ushort_t*)carve((size_t)8192 * 1024 * 2);
  ushort_t* xres  = (ushort_t*)carve((size_t)8192 * 1024 * 2);
  ushort_t* x2    = (ushort_t*)carve((size_t)8192 * 1024 * 2);
  ushort_t* hbuf  = (ushort_t*)carve((size_t)8192 * 4096 * 2);
  ushort_t* vtg   = x1;  // x1 dead after QKV GEMM; reuse

  tcvt_ker<<<dim3(16, 16), 256, 0, stream>>>(Wq, WqkvT, 1024, 1024);
  tcvt_ker<<<dim3(16, 16), 256, 0, stream>>>(Wk, WqkvT + (size_t)1024 * 1024, 1024, 1024);
  tcvt_ker<<<dim3(16, 16), 256, 0, stream>>>(Wv, WqkvT + (size_t)2048 * 1024, 1024, 1024);
  tcvt_ker<<<dim3(16, 16), 256, 0, stream>>>(Wo, WoT, 1024, 1024);
  tcvt_ker<<<dim3(64, 16), 256, 0, stream>>>(W1, W1T, 1024, 4096);
  tcvt_ker<<<dim3(16, 64), 256, 0, stream>>>(W2, W2T, 4096, 1024);
  concat3_ker<<<12, 256, 0, stream>>>(bq, bk, bv, bqkv);
  mbias_ker<<<32, 256, 0, stream>>>(emask, mb);

  ln_ker<<<2048, 256, 0, stream>>>(x, ln1g, ln1b, x1);
  gemm8_ker<0, 256, 128><<<dim3(24, 32), 512, 0, stream>>>(x1, WqkvT, bqkv, nullptr,
                                                           qkvb, 8192, 3072, 1024);
  vtrans_ker<<<dim3(16, 128), 256, 0, stream>>>(qkvb, vtg);
  attn_ker<<<dim3(8, 128), 256, 0, stream>>>(qkvb, vtg, mb, attnb);
  gemm8_ker<3, 128, 128><<<dim3(8, 64), 512, 0, stream>>>(attnb, WoT, bo, x, xres,
                                                          8192, 1024, 1024);
  ln_bf16_ker<<<2048, 256, 0, stream>>>(xres, ln2g, ln2b, x2);
  gemm8_ker<1, 256, 256><<<dim3(16, 32), 512, 0, stream>>>(x2, W1T, b1, nullptr, hbuf,
                                                           8192, 4096, 1024);
  gemm8_ker<4, 128, 128><<<dim3(8, 64), 512, 0, stream>>>(hbuf, W2T, b2, xres,
                                                          (float*)d_out, 8192, 1024, 4096);
}

// Round 10
// 339.369 us; speedup vs baseline: 1.0076x; 1.0076x over previous
//
#include <hip/hip_runtime.h>
#include <hip/hip_bf16.h>

typedef __attribute__((ext_vector_type(4))) float f32x4;
typedef __attribute__((ext_vector_type(8))) short short8;
typedef __attribute__((ext_vector_type(4))) short short4v;
typedef __attribute__((ext_vector_type(2))) unsigned int u32x2;
typedef unsigned short ushort_t;

__device__ __forceinline__ f32x4 mfma16(short8 a, short8 b, f32x4 c) {
  return __builtin_amdgcn_mfma_f32_16x16x32_bf16(a, b, c, 0, 0, 0);
}

__device__ __forceinline__ void gload_lds16(const void* g, void* l) {
  __builtin_amdgcn_global_load_lds(
      (const __attribute__((address_space(1))) void*)g,
      (__attribute__((address_space(3))) void*)l, 16, 0, 0);
}

__device__ __forceinline__ ushort_t f2bf(float f) {
  union { float f; unsigned int u; } un; un.f = f;
  unsigned int u = un.u;
  u += 0x7fffu + ((u >> 16) & 1u);  // round-to-nearest-even
  return (ushort_t)(u >> 16);
}

__device__ __forceinline__ float bf2f(ushort_t u) {
  union { unsigned int i; float f; } c; c.i = ((unsigned int)u) << 16;
  return c.f;
}

__device__ __forceinline__ float fast_exp2(float x) {
#if __has_builtin(__builtin_amdgcn_exp2f)
  return __builtin_amdgcn_exp2f(x);
#else
  return exp2f(x);
#endif
}

__device__ __forceinline__ unsigned int cvt_pk_bf16(float a, float b) {
  unsigned int r;
  asm("v_cvt_pk_bf16_f32 %0, %1, %2" : "=v"(r) : "v"(a), "v"(b));
  return r;
}

// ---------------------------------------------------------------------------
// fp32 (R x C) -> bf16 transposed (C x R)
// ---------------------------------------------------------------------------
__global__ __launch_bounds__(256) void tcvt_ker(const float* __restrict__ in,
                                                ushort_t* __restrict__ out,
                                                int R, int C) {
  __shared__ float t[64][65];
  const int tid = threadIdx.x;
  const int tr = blockIdx.y * 64;
  const int tc = blockIdx.x * 64;
#pragma unroll
  for (int it = 0; it < 4; ++it) {
    int r = it * 16 + (tid >> 4);
    int c4 = (tid & 15) * 4;
    f32x4 v = *(const f32x4*)&in[(size_t)(tr + r) * C + tc + c4];
#pragma unroll
    for (int e = 0; e < 4; ++e) t[r][c4 + e] = v[e];
  }
  __syncthreads();
#pragma unroll
  for (int it = 0; it < 4; ++it) {
    int idx = it * 256 + tid;
    int n = idx >> 4;
    int k4 = (idx & 15) * 4;
    short4v o;
#pragma unroll
    for (int e = 0; e < 4; ++e) o[e] = (short)f2bf(t[k4 + e][n]);
    *(short4v*)&out[(size_t)(tc + n) * R + tr + k4] = o;
  }
}

__global__ __launch_bounds__(256) void concat3_ker(const float* __restrict__ a,
                                                   const float* __restrict__ b,
                                                   const float* __restrict__ c,
                                                   float* __restrict__ o) {
  int i = blockIdx.x * 256 + threadIdx.x;
  if (i < 3072) o[i] = i < 1024 ? a[i] : (i < 2048 ? b[i - 1024] : c[i - 2048]);
}

// mask -> additive float bias (0 or -1e9)
__global__ __launch_bounds__(256) void mbias_ker(const int* __restrict__ emask,
                                                 float* __restrict__ mb) {
  int i = blockIdx.x * 256 + threadIdx.x;
  if (i < 8192) mb[i] = emask[i] ? 0.f : -1e9f;
}

// ---------------------------------------------------------------------------
// LayerNorm, f32 input variant. One wave per row of 1024.
// ---------------------------------------------------------------------------
__global__ __launch_bounds__(256) void ln_ker(const float* __restrict__ x,
                                              const float* __restrict__ g,
                                              const float* __restrict__ b,
                                              ushort_t* __restrict__ out) {
  const int wave = threadIdx.x >> 6, lane = threadIdx.x & 63;
  const size_t row = (size_t)blockIdx.x * 4 + wave;
  const float* xr = x + row * 1024;
  f32x4 v[4];
  float s = 0.f, sq = 0.f;
#pragma unroll
  for (int jj = 0; jj < 4; ++jj) {
    v[jj] = *(const f32x4*)&xr[lane * 4 + jj * 256];
#pragma unroll
    for (int e = 0; e < 4; ++e) { s += v[jj][e]; sq += v[jj][e] * v[jj][e]; }
  }
#pragma unroll
  for (int off = 1; off < 64; off <<= 1) {
    s += __shfl_xor(s, off);
    sq += __shfl_xor(sq, off);
  }
  const float mu = s * (1.0f / 1024.0f);
  const float var = sq * (1.0f / 1024.0f) - mu * mu;
  const float rst = rsqrtf(var + 1e-6f);
#pragma unroll
  for (int jj = 0; jj < 4; ++jj) {
    int col = lane * 4 + jj * 256;
    f32x4 gv = *(const f32x4*)&g[col];
    f32x4 bv = *(const f32x4*)&b[col];
    short4v o;
#pragma unroll
    for (int e = 0; e < 4; ++e)
      o[e] = (short)f2bf((v[jj][e] - mu) * rst * gv[e] + bv[e]);
    *(short4v*)&out[row * 1024 + col] = o;
  }
}

// ---------------------------------------------------------------------------
// LayerNorm, bf16 input variant. One wave per row of 1024.
// ---------------------------------------------------------------------------
__global__ __launch_bounds__(256) void ln_bf16_ker(const ushort_t* __restrict__ x,
                                                   const float* __restrict__ g,
                                                   const float* __restrict__ b,
                                                   ushort_t* __restrict__ out) {
  const int wave = threadIdx.x >> 6, lane = threadIdx.x & 63;
  const size_t row = (size_t)blockIdx.x * 4 + wave;
  const ushort_t* xr = x + row * 1024;
  float vf[16];
  float s = 0.f, sq = 0.f;
#pragma unroll
  for (int jj = 0; jj < 2; ++jj) {
    short8 v8 = *(const short8*)&xr[lane * 8 + jj * 512];
#pragma unroll
    for (int e = 0; e < 8; ++e) {
      float f = bf2f((ushort_t)v8[e]);
      vf[jj * 8 + e] = f;
      s += f; sq += f * f;
    }
  }
#pragma unroll
  for (int off = 1; off < 64; off <<= 1) {
    s += __shfl_xor(s, off);
    sq += __shfl_xor(sq, off);
  }
  const float mu = s * (1.0f / 1024.0f);
  const float var = sq * (1.0f / 1024.0f) - mu * mu;
  const float rst = rsqrtf(var + 1e-6f);
#pragma unroll
  for (int jj = 0; jj < 2; ++jj) {
    int col = lane * 8 + jj * 512;
    short8 o;
#pragma unroll
    for (int q = 0; q < 2; ++q) {
      f32x4 gv = *(const f32x4*)&g[col + q * 4];
      f32x4 bv = *(const f32x4*)&b[col + q * 4];
#pragma unroll
      for (int e = 0; e < 4; ++e)
        o[q * 4 + e] =
            (short)f2bf((vf[jj * 8 + q * 4 + e] - mu) * rst * gv[e] + bv[e]);
    }
    *(short8*)&out[row * 1024 + col] = o;
  }
}

// ---------------------------------------------------------------------------
// V pre-transpose: qkv V block -> Vt[bh][d][kv + kappa], kappa = (k&15)*4+(k>>4)
// ---------------------------------------------------------------------------
__global__ __launch_bounds__(256) void vtrans_ker(const ushort_t* __restrict__ qkv,
                                                  ushort_t* __restrict__ vt) {
  __shared__ ushort_t l[64][72];
  const int tid = threadIdx.x;
  const int tile = blockIdx.x;
  const int bh = blockIdx.y;
  const int b = bh >> 4, h = bh & 15;
  const size_t base = (size_t)b * 1024 * 3072 + 2048 + h * 64;
#pragma unroll
  for (int it = 0; it < 2; ++it) {
    int idx = it * 256 + tid;
    int row = idx >> 3, c8 = (idx & 7) * 8;
    short8 v = *(const short8*)(qkv + base + (size_t)(tile * 64 + row) * 3072 + c8);
    *(short8*)&l[row][c8] = v;
  }
  __syncthreads();
#pragma unroll
  for (int it = 0; it < 2; ++it) {
    int idx = it * 256 + tid;
    int d = idx >> 3, k0 = (idx & 7) * 8;
    short8 o;
#pragma unroll
    for (int m = 0; m < 8; ++m) {
      int kp = k0 + m;
      int key = (kp & 3) * 16 + (kp >> 2);
      o[m] = (short)l[key][d];
    }
    *(short8*)&vt[((size_t)bh * 64 + d) * 1024 + tile * 64 + k0] = o;
  }
}

// ---------------------------------------------------------------------------
// 4-phase GEMM, 2 K-tiles per loop iteration (STATIC buffer bases).
// Per K-tile u in buffer CUR (calendar identical to rounds 5-9):
//  ph0: read fa(A0),fb0 ; stage A1(u+1)->NXT ; BAR ; MFMA(A0,B0) ; BAR
//  ph1: read fb1        ; stage A0(u+2)->CUR ; BAR ; MFMA(A0,B1) ; BAR
//  ph2: read fa(A1)     ; stage B0(u+2)->CUR ; BAR ; MFMA(A1,B1) ; BAR
//  ph3:                   stage B1(u+2)->CUR ; BAR ; MFMA(A1,B0) ; vmcnt(VN) ; BAR
// CUR/NXT are compile-time -> all ds_read/stage LDS addresses fold to
// base+immediate (kills the 23% VALUBusy address recompute).
// MODE 0: bf16 | 1: bf16+relu | 3: bf16 + f32 resid | 4: f32 + bf16 resid
// ---------------------------------------------------------------------------
template <int MODE, int BM, int BN>
__global__ __launch_bounds__(512, 1) void gemm8_ker(
    const ushort_t* __restrict__ A, const ushort_t* __restrict__ Bt,
    const float* __restrict__ bias, const void* __restrict__ resid,
    void* __restrict__ Cout, int M, int N, int K) {
  constexpr int MR = BM / 32;
  constexpr int NR = BN / 64;
  constexpr int LA = BM / 128;
  constexpr int LB = BN / 128;
  constexpr int HALF_A = (BM / 2) * 128;
  constexpr int HALF_B = (BN / 2) * 128;
  constexpr int TILE = 2 * HALF_A + 2 * HALF_B;
  constexpr int VN = LA + 2 * LB;

  __shared__ alignas(128) char lds[2 * TILE];

  const int tid = threadIdx.x;
  const int wave = tid >> 6, lane = tid & 63;
  const int g = lane >> 4, l15 = lane & 15;
  const int wr = wave >> 2, wc = wave & 3;

  const int nwg = gridDim.x * gridDim.y;
  int wg = blockIdx.y * gridDim.x + blockIdx.x;
  if ((nwg & 7) == 0) wg = (wg & 7) * (nwg >> 3) + (wg >> 3);
  const int bx = wg % gridDim.x, by = wg / gridDim.x;
  const int mbase = by * BM;
  const int nbase = bx * BN;
  const int NT = K >> 6;  // always even here (K = 1024 or 4096)

  auto stage_A = [&](int bf, int h, int kt) {
    const ushort_t* sb = A + (size_t)(mbase + h * (BM / 2)) * K + kt * 64;
    char* dst = lds + bf * TILE + h * HALF_A;
#pragma unroll
    for (int it = 0; it < LA; ++it) {
      int li = it * 512 + tid;
      int r = li >> 3;
      int cs = ((tid & 7) * 16) ^ ((r & 7) << 4);
      gload_lds16((const char*)(sb + (size_t)r * K) + cs, dst + li * 16);
    }
  };
  auto stage_B = [&](int bf, int h, int kt) {
    const ushort_t* sb = Bt + (size_t)(nbase + h * (BN / 2)) * K + kt * 64;
    char* dst = lds + bf * TILE + 2 * HALF_A + h * HALF_B;
#pragma unroll
    for (int it = 0; it < LB; ++it) {
      int li = it * 512 + tid;
      int r = li >> 3;
      int cs = ((tid & 7) * 16) ^ ((r & 7) << 4);
      gload_lds16((const char*)(sb + (size_t)r * K) + cs, dst + li * 16);
    }
  };
  auto frag = [&](const char* slot, int r, int kk) -> short8 {
    const int cb = kk * 64 + g * 16;
    return *(const short8*)(slot + r * 128 + (cb ^ ((r & 7) << 4)));
  };

  f32x4 acc[MR][NR];
  const f32x4 zf = {0.f, 0.f, 0.f, 0.f};
#pragma unroll
  for (int i = 0; i < MR; ++i)
#pragma unroll
    for (int j = 0; j < NR; ++j) acc[i][j] = zf;

  // prologue: tile0 fully + tile1 {A0,B0,B1}; vmcnt leaves exactly those 3 halves
  stage_A(0, 0, 0); stage_A(0, 1, 0); stage_B(0, 0, 0); stage_B(0, 1, 0);
  stage_A(1, 0, 1); stage_B(1, 0, 1); stage_B(1, 1, 1);
  asm volatile("s_waitcnt vmcnt(%0)" :: "n"(VN) : "memory");
  __builtin_amdgcn_s_barrier();

  short8 fa[MR / 2][2], fb0[NR / 2][2], fb1[NR / 2][2];

#define GEMM_KTILE(CUR, NXT, T)                                               \
  {                                                                           \
    const int k1 = ((T) + 1 < NT) ? (T) + 1 : NT - 1;                         \
    const int k2 = ((T) + 2 < NT) ? (T) + 2 : NT - 1;                         \
    const char* sA0 = lds + (CUR) * TILE;                                     \
    const char* sA1 = sA0 + HALF_A;                                           \
    const char* sB0 = sA0 + 2 * HALF_A;                                       \
    const char* sB1 = sB0 + HALF_B;                                           \
    _Pragma("unroll") for (int ii = 0; ii < MR / 2; ++ii)                     \
        _Pragma("unroll") for (int kk = 0; kk < 2; ++kk)                      \
            fa[ii][kk] = frag(sA0, wr * (BM / 4) + ii * 16 + l15, kk);        \
    _Pragma("unroll") for (int jj = 0; jj < NR / 2; ++jj)                     \
        _Pragma("unroll") for (int kk = 0; kk < 2; ++kk)                      \
            fb0[jj][kk] = frag(sB0, wc * (BN / 8) + jj * 16 + l15, kk);       \
    stage_A((NXT), 1, k1);                                                    \
    __builtin_amdgcn_s_barrier();                                             \
    __builtin_amdgcn_s_setprio(1);                                            \
    _Pragma("unroll") for (int ii = 0; ii < MR / 2; ++ii)                     \
        _Pragma("unroll") for (int jj = 0; jj < NR / 2; ++jj)                 \
            _Pragma("unroll") for (int kk = 0; kk < 2; ++kk)                  \
                acc[ii][jj] = mfma16(fa[ii][kk], fb0[jj][kk], acc[ii][jj]);   \
    __builtin_amdgcn_s_setprio(0);                                            \
    _Pragma("unroll") for (int jj = 0; jj < NR / 2; ++jj)                     \
        _Pragma("unroll") for (int kk = 0; kk < 2; ++kk)                      \
            fb1[jj][kk] = frag(sB1, wc * (BN / 8) + jj * 16 + l15, kk);       \
    __builtin_amdgcn_s_barrier();                                             \
    stage_A((CUR), 0, k2);                                                    \
    __builtin_amdgcn_s_barrier();                                             \
    __builtin_amdgcn_s_setprio(1);                                            \
    _Pragma("unroll") for (int ii = 0; ii < MR / 2; ++ii)                     \
        _Pragma("unroll") for (int jj = 0; jj < NR / 2; ++jj)                 \
            _Pragma("unroll") for (int kk = 0; kk < 2; ++kk)                  \
                acc[ii][jj + NR / 2] =                                        \
                    mfma16(fa[ii][kk], fb1[jj][kk], acc[ii][jj + NR / 2]);    \
    __builtin_amdgcn_s_setprio(0);                                            \
    _Pragma("unroll") for (int ii = 0; ii < MR / 2; ++ii)                     \
        _Pragma("unroll") for (int kk = 0; kk < 2; ++kk)                      \
            fa[ii][kk] = frag(sA1, wr * (BM / 4) + ii * 16 + l15, kk);        \
    __builtin_amdgcn_s_barrier();                                             \
    stage_B((CUR), 0, k2);                                                    \
    __builtin_amdgcn_s_barrier();                                             \
    __builtin_amdgcn_s_setprio(1);                                            \
    _Pragma("unroll") for (int ii = 0; ii < MR / 2; ++ii)                     \
        _Pragma("unroll") for (int jj = 0; jj < NR / 2; ++jj)                 \
            _Pragma("unroll") for (int kk = 0; kk < 2; ++kk)                  \
                acc[ii + MR / 2][jj + NR / 2] = mfma16(                       \
                    fa[ii][kk], fb1[jj][kk], acc[ii + MR / 2][jj + NR / 2]);  \
    __builtin_amdgcn_s_setprio(0);                                            \
    __builtin_amdgcn_s_barrier();                                             \
    stage_B((CUR), 1, k2);                                                    \
    __builtin_amdgcn_s_barrier();                                             \
    __builtin_amdgcn_s_setprio(1);                                            \
    _Pragma("unroll") for (int ii = 0; ii < MR / 2; ++ii)                     \
        _Pragma("unroll") for (int jj = 0; jj < NR / 2; ++jj)                 \
            _Pragma("unroll") for (int kk = 0; kk < 2; ++kk)                  \
                acc[ii + MR / 2][jj] =                                        \
                    mfma16(fa[ii][kk], fb0[jj][kk], acc[ii + MR / 2][jj]);    \
    __builtin_amdgcn_s_setprio(0);                                            \
    asm volatile("s_waitcnt vmcnt(%0)" :: "n"(VN) : "memory");                \
    __builtin_amdgcn_s_barrier();                                             \
  }

  for (int t = 0; t < NT; t += 2) {
    GEMM_KTILE(0, 1, t);
    GEMM_KTILE(1, 0, t + 1);
  }
#undef GEMM_KTILE

  asm volatile("s_waitcnt vmcnt(0)" ::: "memory");

  float bcol[NR];
#pragma unroll
  for (int j = 0; j < NR; ++j) {
    const int bandj = j / (NR / 2), jj = j % (NR / 2);
    bcol[j] = bias[nbase + bandj * (BN / 2) + wc * (BN / 8) + jj * 16 + l15];
  }
#pragma unroll
  for (int i = 0; i < MR; ++i) {
    const int band = i / (MR / 2), ii = i % (MR / 2);
    const int rowb = mbase + band * (BM / 2) + wr * (BM / 4) + ii * 16 + g * 4;
#pragma unroll
    for (int r = 0; r < 4; ++r) {
      const int row = rowb + r;
#pragma unroll
      for (int j = 0; j < NR; ++j) {
        const int bandj = j / (NR / 2), jj = j % (NR / 2);
        const int col = nbase + bandj * (BN / 2) + wc * (BN / 8) + jj * 16 + l15;
        float v = acc[i][j][r] + bcol[j];
        if (MODE == 4) {
          float rv = bf2f(((const ushort_t*)resid)[(size_t)row * N + col]);
          ((float*)Cout)[(size_t)row * N + col] = rv + v;
        } else if (MODE == 3) {
          float rv = ((const float*)resid)[(size_t)row * N + col];
          ((ushort_t*)Cout)[(size_t)row * N + col] = f2bf(rv + v);
        } else {
          if (MODE == 1) v = fmaxf(v, 0.f);
          ((ushort_t*)Cout)[(size_t)row * N + col] = f2bf(v);
        }
      }
    }
  }
}

// ---------------------------------------------------------------------------
// Flash attention v5 (unchanged)
// ---------------------------------------------------------------------------
__global__ __launch_bounds__(256, 4) void attn_ker(const ushort_t* __restrict__ qkv,
                                                   const ushort_t* __restrict__ vt,
                                                   const float* __restrict__ mbias,
                                                   ushort_t* __restrict__ out) {
  __shared__ ushort_t lK[2][4096];
  __shared__ ushort_t lV[2][4096];
  __shared__ ushort_t lP[4][1024];
  const int tid = threadIdx.x;
  const int wave = tid >> 6, lane = tid & 63;
  const int g = lane >> 4, l15 = lane & 15;
  const int orig = blockIdx.y * 8 + blockIdx.x;
  const int swz = (orig & 7) * 128 + (orig >> 3);
  const int qp = swz & 7;
  const int bh = swz >> 3;
  const int b = bh >> 4, h = bh & 15;
  const int QS = 3072;
  const size_t base = (size_t)b * 1024 * QS;
  const int qoff = h * 64, koff = 1024 + h * 64;

  short8 qf[2][2];
#pragma unroll
  for (int s = 0; s < 2; ++s) {
    const int qrow = qp * 128 + s * 64 + wave * 16 + l15;
    const ushort_t* qpt = qkv + base + (size_t)qrow * QS + qoff + g * 8;
    qf[s][0] = *(const short8*)(qpt);
    qf[s][1] = *(const short8*)(qpt + 32);
  }
  f32x4 lsum4[2];
  f32x4 acco[2][4];
  const f32x4 zf = {0.f, 0.f, 0.f, 0.f};
#pragma unroll
  for (int s = 0; s < 2; ++s) {
    lsum4[s] = zf;
#pragma unroll
    for (int dj = 0; dj < 4; ++dj) acco[s][dj] = zf;
  }

  const float SCL = 0.125f * 1.44269504089f;
  const float* mbp = mbias + b * 1024 + l15;

  const int itrow = tid >> 3;
  const int c16 = ((tid & 7) * 16) ^ ((itrow & 7) << 4);
  const char* srcK = (const char*)(qkv + base + (size_t)itrow * QS + koff) + c16;
  const char* srcV = (const char*)(vt + ((size_t)bh * 64 + itrow) * 1024) + c16;
  constexpr int K_IT = 32 * 3072 * 2;
  constexpr int K_T  = 64 * 3072 * 2;
  constexpr int V_IT = 32 * 1024 * 2;
  constexpr int V_T  = 64 * 2;

  auto stage = [&](int bufi) {
    gload_lds16(srcK, &lK[bufi][tid * 8]);
    gload_lds16(srcK + K_IT, &lK[bufi][2048 + tid * 8]);
    gload_lds16(srcV, &lV[bufi][tid * 8]);
    gload_lds16(srcV + V_IT, &lV[bufi][2048 + tid * 8]);
  };

  stage(0);
  srcK += K_T; srcV += V_T;
  __syncthreads();

  for (int t = 0; t < 16; ++t) {
    const int buf = t & 1;
    if (t < 15) {
      stage(buf ^ 1);
      srcK += K_T; srcV += V_T;
    }
    const int kv = t * 64;
    float mbv[4];
#pragma unroll
    for (int j = 0; j < 4; ++j) mbv[j] = mbp[kv + j * 16];

    ushort_t* lPw = lP[wave];
#pragma unroll
    for (int s = 0; s < 2; ++s) {
      f32x4 sv[4];
#pragma unroll
      for (int j = 0; j < 4; ++j) {
        const int row = j * 16 + l15;
        const int sw = (l15 & 7) << 3;
        const short8 b0 = *(const short8*)&lK[buf][row * 64 + ((g * 8) ^ sw)];
        const short8 b1 = *(const short8*)&lK[buf][row * 64 + ((32 + g * 8) ^ sw)];
        f32x4 t2 = mfma16(qf[s][0], b0, zf);
        t2 = mfma16(qf[s][1], b1, t2);
#pragma unroll
        for (int e = 0; e < 4; ++e) t2[e] = t2[e] * SCL + mbv[j];
        sv[j] = t2;
      }

#pragma unroll
      for (int j = 0; j < 4; ++j) {
#pragma unroll
        for (int e = 0; e < 4; ++e) sv[j][e] = fast_exp2(sv[j][e]);
        lsum4[s] += sv[j];
      }

#pragma unroll
      for (int r = 0; r < 4; ++r) {
        const int q = g * 4 + r;
        u32x2 pk;
        pk[0] = cvt_pk_bf16(sv[0][r], sv[1][r]);
        pk[1] = cvt_pk_bf16(sv[2][r], sv[3][r]);
        *(u32x2*)&lPw[q * 64 + ((l15 * 4) ^ ((q & 7) << 3))] = pk;
      }

#pragma unroll
      for (int kk = 0; kk < 2; ++kk) {
        const short8 pa =
            *(const short8*)&lPw[l15 * 64 + ((kk * 32 + g * 8) ^ ((l15 & 7) << 3))];
#pragma unroll
        for (int dj = 0; dj < 4; ++dj) {
          const int drow = dj * 16 + l15;
          const short8 vb =
              *(const short8*)&lV[buf][drow * 64 + ((kk * 32 + g * 8) ^ ((drow & 7) << 3))];
          acco[s][dj] = mfma16(pa, vb, acco[s][dj]);
        }
      }
    }
    __syncthreads();
  }

#pragma unroll
  for (int s = 0; s < 2; ++s) {
#pragma unroll
    for (int r = 0; r < 4; ++r) {
      float tot = lsum4[s][r];
      tot += __shfl_xor(tot, 1);
      tot += __shfl_xor(tot, 2);
      tot += __shfl_xor(tot, 4);
      tot += __shfl_xor(tot, 8);
      const float inv = 1.0f / tot;
      const int row = qp * 128 + s * 64 + wave * 16 + g * 4 + r;
#pragma unroll
      for (int dj = 0; dj < 4; ++dj)
        out[((size_t)(b * 1024 + row)) * 1024 + h * 64 + dj * 16 + l15] =
            f2bf(acco[s][dj][r] * inv);
    }
  }
}

// ---------------------------------------------------------------------------
extern "C" void kernel_launch(void* const* d_in, const int* in_sizes, int n_in,
                              void* d_out, int out_size, void* d_ws, size_t ws_size,
                              hipStream_t stream) {
  const float* x    = (const float*)d_in[0];
  const int* emask  = (const int*)d_in[1];
  const float* ln1g = (const float*)d_in[2];
  const float* ln1b = (const float*)d_in[3];
  const float* Wq   = (const float*)d_in[4];
  const float* bq   = (const float*)d_in[5];
  const float* Wk   = (const float*)d_in[6];
  const float* bk   = (const float*)d_in[7];
  const float* Wv   = (const float*)d_in[8];
  const float* bv   = (const float*)d_in[9];
  const float* Wo   = (const float*)d_in[10];
  const float* bo   = (const float*)d_in[11];
  const float* ln2g = (const float*)d_in[12];
  const float* ln2b = (const float*)d_in[13];
  const float* W1   = (const float*)d_in[14];
  const float* b1   = (const float*)d_in[15];
  const float* W2   = (const float*)d_in[16];
  const float* b2   = (const float*)d_in[17];

  char* p = (char*)d_ws;
  auto carve = [&](size_t bytes) {
    char* r = p;
    p += (bytes + 255) & ~(size_t)255;
    return r;
  };
  ushort_t* WqkvT = (ushort_t*)carve((size_t)3072 * 1024 * 2);
  ushort_t* WoT   = (ushort_t*)carve((size_t)1024 * 1024 * 2);
  ushort_t* W1T   = (ushort_t*)carve((size_t)4096 * 1024 * 2);
  ushort_t* W2T   = (ushort_t*)carve((size_t)1024 * 4096 * 2);
  float*    bqkv  = (float*)carve(3072 * 4);
  float*    mb    = (float*)carve(8192 * 4);
  ushort_t* x1    = (ushort_t*)carve((size_t)8192 * 1024 * 2);
  ushort_t* qkvb  = (ushort_t*)carve((size_t)8192 * 3072 * 2);
  ushort_t* attnb = (ushort_t*)carve((size_t)8192 * 1024 * 2);
  ushort_t* xres  = (ushort_t*)carve((size_t)8192 * 1024 * 2);
  ushort_t* x2    = (ushort_t*)carve((size_t)8192 * 1024 * 2);
  ushort_t* hbuf  = (ushort_t*)carve((size_t)8192 * 4096 * 2);
  ushort_t* vtg   = x1;  // x1 dead after QKV GEMM; reuse

  tcvt_ker<<<dim3(16, 16), 256, 0, stream>>>(Wq, WqkvT, 1024, 1024);
  tcvt_ker<<<dim3(16, 16), 256, 0, stream>>>(Wk, WqkvT + (size_t)1024 * 1024, 1024, 1024);
  tcvt_ker<<<dim3(16, 16), 256, 0, stream>>>(Wv, WqkvT + (size_t)2048 * 1024, 1024, 1024);
  tcvt_ker<<<dim3(16, 16), 256, 0, stream>>>(Wo, WoT, 1024, 1024);
  tcvt_ker<<<dim3(64, 16), 256, 0, stream>>>(W1, W1T, 1024, 4096);
  tcvt_ker<<<dim3(16, 64), 256, 0, stream>>>(W2, W2T, 4096, 1024);
  concat3_ker<<<12, 256, 0, stream>>>(bq, bk, bv, bqkv);
  mbias_ker<<<32, 256, 0, stream>>>(emask, mb);

  ln_ker<<<2048, 256, 0, stream>>>(x, ln1g, ln1b, x1);
  gemm8_ker<0, 256, 128><<<dim3(24, 32), 512, 0, stream>>>(x1, WqkvT, bqkv, nullptr,
                                                           qkvb, 8192, 3072, 1024);
  vtrans_ker<<<dim3(16, 128), 256, 0, stream>>>(qkvb, vtg);
  attn_ker<<<dim3(8, 128), 256, 0, stream>>>(qkvb, vtg, mb, attnb);
  gemm8_ker<3, 128, 128><<<dim3(8, 64), 512, 0, stream>>>(attnb, WoT, bo, x, xres,
                                                          8192, 1024, 1024);
  ln_bf16_ker<<<2048, 256, 0, stream>>>(xres, ln2g, ln2b, x2);
  gemm8_ker<1, 256, 256><<<dim3(16, 32), 512, 0, stream>>>(x2, W1T, b1, nullptr, hbuf,
                                                           8192, 4096, 1024);
  gemm8_ker<4, 128, 128><<<dim3(8, 64), 512, 0, stream>>>(hbuf, W2T, b2, xres,
                                                          (float*)d_out, 8192, 1024, 4096);
}